// Round 9
// baseline (211.568 us; speedup 1.0000x reference)
//
#include <hip/hip_runtime.h>

#define TT 48
#define DD 32
#define HH 64
#define BB 16384

typedef __bf16 bf16x8 __attribute__((ext_vector_type(8)));
typedef float f32x4 __attribute__((ext_vector_type(4)));
typedef unsigned short us4 __attribute__((ext_vector_type(4)));

#define MFMA(a, b, c) __builtin_amdgcn_mfma_f32_16x16x32_bf16(a, b, c, 0, 0, 0)
#define BC(v) __builtin_bit_cast(bf16x8, v)

static __device__ __forceinline__ unsigned short bfu(float f) {
  __bf16 b = (__bf16)f;
  return __builtin_bit_cast(unsigned short, b);
}
static __device__ __forceinline__ float bff(unsigned short u) {
  return (float)__builtin_bit_cast(__bf16, u);
}
static __device__ __forceinline__ float sigm(float v) {
  return __builtin_amdgcn_rcpf(1.f + __expf(-v));
}
static __device__ __forceinline__ float tanh_f(float v) {
  // 1 - 2/(1+e^{2x}); saturates correctly at +-inf
  return fmaf(-2.f, __builtin_amdgcn_rcpf(1.f + __expf(2.f * v)), 1.f);
}

// ------------------------------------------------------------------
// Row bijection: tile m = g*4+hq (g = gate), tile-row = qp*4+r.
//   hidx(hq,qp,r) = (hq>>1)*32 + qp*8 + (hq&1)*4 + r
// Lane (b,qp)'s D outputs == exactly its next-step B-fragment slots ->
// h never leaves the lane: zero LDS/shuffle/barrier in the recurrence.
// ------------------------------------------------------------------

// Kernel 0: linearize W into per-lane MFMA A-fragment order with the bijection.
__global__ void prep_kernel(const float* __restrict__ W_ih, const float* __restrict__ W_hh,
                            const float* __restrict__ b_ih, const float* __restrict__ b_hh,
                            unsigned short* __restrict__ WhhL, unsigned short* __restrict__ WihL,
                            float* __restrict__ bsumL) {
  const int tid = threadIdx.x;  // 256 threads, 1 block
  const int l = tid & 63, qt = tid >> 6;
  const int rowl = l & 15, kq = (l >> 4) * 8;
  for (int mm = 0; mm < 4; ++mm) {
    const int m = qt * 4 + mm;
    const int g = m >> 2, hq = m & 3;
    const int hidx = (hq >> 1) * 32 + (rowl >> 2) * 8 + (hq & 1) * 4 + (rowl & 3);
    const int orig = g * 64 + hidx;
    for (int c = 0; c < 2; ++c)
      for (int j = 0; j < 8; ++j) {
        float w = W_hh[orig * 64 + c * 32 + kq + j];
        unsigned short hi = bfu(w);
        WhhL[((0 * 16 + m) * 2 + c) * 512 + l * 8 + j] = hi;
        WhhL[((1 * 16 + m) * 2 + c) * 512 + l * 8 + j] = bfu(w - bff(hi));
      }
    for (int j = 0; j < 8; ++j)
      WihL[m * 512 + l * 8 + j] = bfu(W_ih[orig * 32 + kq + j]);
    if ((l >> 4) == 0) bsumL[m * 16 + rowl] = b_ih[orig] + b_hh[orig];
  }
}

// ------------------------------------------------------------------
// Kernel 1: attention + fused xw precompute.
// a[b,:] = softmax_d( sum_t x[b,t,d]*w_att[2H+t] ) (h/c/b_att terms are
// uniform over d -> softmax-invariant -> dropped). Writes out0 = a broadcast,
// AND xw[b][t][d] = a[b][d]*x[b][t][d] as 32 bf16 packed into the TAIL 64B
// (floats [48,64)) of out1 row (b,t) — lstm reads it there at step t and then
// overwrites the tail with the real h values.
// ------------------------------------------------------------------
__global__ __launch_bounds__(256) void attn_kernel(const float* __restrict__ x,
                                                   const float* __restrict__ W_att,
                                                   float* __restrict__ out0,
                                                   float* __restrict__ out1) {
  int tid = threadIdx.x;
  int b = blockIdx.x * 32 + (tid >> 3);
  int dq = (tid & 7) * 4;
  const float* xb = x + (size_t)b * (TT * DD);
  float px = 0.f, py = 0.f, pz = 0.f, pw = 0.f;
#pragma unroll 4
  for (int t = 0; t < TT; ++t) {
    float w = W_att[2 * HH + t];
    float4 xv = *(const float4*)(xb + t * DD + dq);
    px = fmaf(xv.x, w, px);
    py = fmaf(xv.y, w, py);
    pz = fmaf(xv.z, w, pz);
    pw = fmaf(xv.w, w, pw);
  }
  float m = fmaxf(fmaxf(px, py), fmaxf(pz, pw));
#pragma unroll
  for (int s = 1; s < 8; s <<= 1) m = fmaxf(m, __shfl_xor(m, s));
  float ex = __expf(px - m), ey = __expf(py - m), ez = __expf(pz - m), ew = __expf(pw - m);
  float sum = ex + ey + ez + ew;
#pragma unroll
  for (int s = 1; s < 8; s <<= 1) sum += __shfl_xor(sum, s);
  float inv = __builtin_amdgcn_rcpf(sum);
  float4 a;
  a.x = ex * inv; a.y = ey * inv; a.z = ez * inv; a.w = ew * inv;
  float* o = out0 + (size_t)b * (TT * DD) + dq;
  char* xwrow = (char*)(out1 + (size_t)b * (TT * HH)) + 192 + dq * 2;
#pragma unroll 4
  for (int t = 0; t < TT; ++t) {
    float4 xv = *(const float4*)(xb + t * DD + dq);
    *(float4*)(o + t * DD) = a;
    us4 w;
    w.x = bfu(xv.x * a.x);
    w.y = bfu(xv.y * a.y);
    w.z = bfu(xv.z * a.z);
    w.w = bfu(xv.w * a.w);
    *(us4*)(xwrow + (size_t)t * (HH * 4)) = w;
  }
}

// ------------------------------------------------------------------
// Kernel 2: lane-local register-resident LSTM. 256 blocks x 256 thr; each
// wave owns 16 batch rows end-to-end, no LDS exchange/barrier in the T loop.
// 80 MFMAs/step: (Whi+Wlo)*Bhi per 32-chunk + Wih*xw. h kept single-bf16
// (lo dropped: ~1e-3 worst-case absmax, within the 2.1e-3 threshold).
// xw read pre-scaled (bf16) from the out1-row tail written by attn.
// ------------------------------------------------------------------
__global__ __launch_bounds__(256, 1) void lstm_kernel(
    const float* __restrict__ h0, const float* __restrict__ c0,
    const unsigned short* __restrict__ WhhL, const unsigned short* __restrict__ WihL,
    const float* __restrict__ bsumL, float* __restrict__ out1) {
  __shared__ __align__(16) float sbias[256];
  const int tid = threadIdx.x;
  const int l = tid & 63;
  const int wid = tid >> 6;
  const int b = l & 15;
  const int qp = l >> 4;
  const int brow = blockIdx.x * 64 + wid * 16 + b;

  sbias[tid] = bsumL[tid];

  // resident W fragments (f32x4 carriers; bitcast to bf16x8 at use)
  f32x4 whh[2][16][2];
#pragma unroll
  for (int p = 0; p < 2; ++p)
#pragma unroll
    for (int m = 0; m < 16; ++m)
#pragma unroll
      for (int c = 0; c < 2; ++c)
        whh[p][m][c] = *(const f32x4*)(WhhL + (((p * 16 + m) * 2 + c) << 9) + l * 8);
  f32x4 wih[16];
#pragma unroll
  for (int m = 0; m < 16; ++m)
    wih[m] = *(const f32x4*)(WihL + (m << 9) + l * 8);

  // PIN: keep the weight values in registers across the loop
#pragma unroll
  for (int p = 0; p < 2; ++p)
#pragma unroll
    for (int m = 0; m < 16; ++m)
#pragma unroll
      for (int c = 0; c < 2; ++c)
        asm volatile("" : "+v"(whh[p][m][c]));
#pragma unroll
  for (int m = 0; m < 16; ++m) asm volatile("" : "+v"(wih[m]));

  // c state: creg[hq][r] = c[brow][hidx(hq,qp,r)]
  f32x4 creg[4];
#pragma unroll
  for (int hq = 0; hq < 4; ++hq)
    creg[hq] = *(const f32x4*)(c0 + (size_t)brow * HH + (hq >> 1) * 32 + qp * 8 + (hq & 1) * 4);

  // h state as single-bf16 B-fragments: bh[c] elem j = bf16(h[brow][c*32+qp*8+j])
  bf16x8 bh[2];
#pragma unroll
  for (int c = 0; c < 2; ++c) {
    const float* hp = h0 + (size_t)brow * HH + c * 32 + qp * 8;
    float4 v0 = *(const float4*)hp, v1 = *(const float4*)(hp + 4);
    float vv[8] = {v0.x, v0.y, v0.z, v0.w, v1.x, v1.y, v1.z, v1.w};
#pragma unroll
    for (int j = 0; j < 8; ++j) bh[c][j] = (__bf16)vv[j];
  }
  __syncthreads();  // only for sbias staging

  float* op = out1 + (size_t)brow * (TT * HH);
  const char* xwp = (const char*)op + 192 + qp * 16;  // this lane's xw tail slot
  bf16x8 bxw = *(const bf16x8*)(xwp);                 // t = 0

  for (int t = 0; t < TT; ++t) {
    // prefetch next xw (final-iteration load is dead; loads can't corrupt)
    const int tn = (t + 1 < TT) ? (t + 1) : (TT - 1);
    bf16x8 bxn = *(const bf16x8*)(xwp + (size_t)tn * (HH * 4));

    bf16x8 nbh[2];
#pragma unroll
    for (int hq = 0; hq < 4; ++hq) {
      f32x4 acc[4];
#pragma unroll
      for (int g = 0; g < 4; ++g) {
        const int m = g * 4 + hq;
        f32x4 A = *(const f32x4*)(sbias + m * 16 + qp * 4);  // broadcast, conflict-free
        A = MFMA(BC(whh[0][m][0]), bh[0], A);  // k 0..31:  Whi*Bhi
        A = MFMA(BC(whh[1][m][0]), bh[0], A);  //           Wlo*Bhi
        A = MFMA(BC(whh[0][m][1]), bh[1], A);  // k 32..63: Whi*Bhi
        A = MFMA(BC(whh[1][m][1]), bh[1], A);  //           Wlo*Bhi
        A = MFMA(BC(wih[m]), bxw, A);          // input chunk (pre-scaled xw)
        acc[g] = A;
      }
      // pointwise: i/f/g/o lane-local (rows qp*4+r of tiles g*4+hq)
      float hr[4];
#pragma unroll
      for (int r = 0; r < 4; ++r) {
        float ig = sigm(acc[0][r]);
        float fg = sigm(acc[1][r]);
        float gt = tanh_f(acc[2][r]);
        float og = sigm(acc[3][r]);
        float cn = fg * creg[hq][r] + ig * gt;
        creg[hq][r] = cn;
        hr[r] = og * tanh_f(cn);
      }
      // out1: contiguous float4 at hidx base (4 qp-lanes cover the full row)
      float4 hv;
      hv.x = hr[0]; hv.y = hr[1]; hv.z = hr[2]; hv.w = hr[3];
      *(float4*)(op + (size_t)t * HH + (hq >> 1) * 32 + qp * 8 + (hq & 1) * 4) = hv;
      // repack into next step's B-fragment (lane-local, single bf16)
#pragma unroll
      for (int r = 0; r < 4; ++r) nbh[hq >> 1][(hq & 1) * 4 + r] = (__bf16)hr[r];
    }
    bh[0] = nbh[0];
    bh[1] = nbh[1];
    bxw = bxn;
  }
}

extern "C" void kernel_launch(void* const* d_in, const int* in_sizes, int n_in,
                              void* d_out, int out_size, void* d_ws, size_t ws_size,
                              hipStream_t stream) {
  const float* x = (const float*)d_in[0];
  const float* h0 = (const float*)d_in[1];
  const float* c0 = (const float*)d_in[2];
  const float* W_att = (const float*)d_in[3];
  // d_in[4] = b_att: uniform shift, softmax-invariant -> unused
  const float* W_ih = (const float*)d_in[5];
  const float* W_hh = (const float*)d_in[6];
  const float* b_ih = (const float*)d_in[7];
  const float* b_hh = (const float*)d_in[8];

  float* out0 = (float*)d_out;                // attention [B,T,D]
  float* out1 = out0 + (size_t)BB * TT * DD;  // input_encoded [B,T,H]

  char* ws = (char*)d_ws;
  unsigned short* WhhL = (unsigned short*)ws;            // 65536 B
  unsigned short* WihL = (unsigned short*)(ws + 65536);  // 16384 B
  float* bsumL = (float*)(ws + 81920);                   // 1024 B

  prep_kernel<<<1, 256, 0, stream>>>(W_ih, W_hh, b_ih, b_hh, WhhL, WihL, bsumL);
  attn_kernel<<<BB / 32, 256, 0, stream>>>(x, W_att, out0, out1);
  lstm_kernel<<<BB / 64, 256, 0, stream>>>(h0, c0, WhhL, WihL, bsumL, out1);
}

// Round 10
// 164.076 us; speedup vs baseline: 1.2895x; 1.2895x over previous
//
#include <hip/hip_runtime.h>

#define TT 48
#define DD 32
#define HH 64
#define BB 16384

typedef __bf16 bf16x8 __attribute__((ext_vector_type(8)));
typedef float f32x4 __attribute__((ext_vector_type(4)));

#define MFMA(a, b, c) __builtin_amdgcn_mfma_f32_16x16x32_bf16(a, b, c, 0, 0, 0)
#define BC(v) __builtin_bit_cast(bf16x8, v)

static __device__ __forceinline__ unsigned short bfu(float f) {
  __bf16 b = (__bf16)f;
  return __builtin_bit_cast(unsigned short, b);
}
static __device__ __forceinline__ float bff(unsigned short u) {
  return (float)__builtin_bit_cast(__bf16, u);
}
static __device__ __forceinline__ float sigm(float v) {
  return __builtin_amdgcn_rcpf(1.f + __expf(-v));
}
static __device__ __forceinline__ float tanh_f(float v) {
  // 1 - 2/(1+e^{2x}); saturates correctly at +-inf
  return fmaf(-2.f, __builtin_amdgcn_rcpf(1.f + __expf(2.f * v)), 1.f);
}

// ------------------------------------------------------------------
// Row bijection: tile m = g*4+hq, tile-row = qp*4+r.
//   hidx(hq,qp,r) = (hq>>1)*32 + qp*8 + (hq&1)*4 + r
// Wave `half` of a pair owns hq in {2*half, 2*half+1}: its D outputs are
// exactly h-chunk [half*32, half*32+32) = its own next-step B-frag slots.
// The other chunk comes from the partner wave via a 16B/lane LDS exchange.
// ------------------------------------------------------------------

// Kernel 0: linearize W into per-lane MFMA A-fragment order (unchanged layout).
__global__ void prep_kernel(const float* __restrict__ W_ih, const float* __restrict__ W_hh,
                            const float* __restrict__ b_ih, const float* __restrict__ b_hh,
                            unsigned short* __restrict__ WhhL, unsigned short* __restrict__ WihL,
                            float* __restrict__ bsumL) {
  const int tid = threadIdx.x;  // 256 threads, 1 block
  const int l = tid & 63, qt = tid >> 6;
  const int rowl = l & 15, kq = (l >> 4) * 8;
  for (int mm = 0; mm < 4; ++mm) {
    const int m = qt * 4 + mm;
    const int g = m >> 2, hq = m & 3;
    const int hidx = (hq >> 1) * 32 + (rowl >> 2) * 8 + (hq & 1) * 4 + (rowl & 3);
    const int orig = g * 64 + hidx;
    for (int c = 0; c < 2; ++c)
      for (int j = 0; j < 8; ++j) {
        float w = W_hh[orig * 64 + c * 32 + kq + j];
        unsigned short hi = bfu(w);
        WhhL[((0 * 16 + m) * 2 + c) * 512 + l * 8 + j] = hi;
        WhhL[((1 * 16 + m) * 2 + c) * 512 + l * 8 + j] = bfu(w - bff(hi));
      }
    for (int j = 0; j < 8; ++j)
      WihL[m * 512 + l * 8 + j] = bfu(W_ih[orig * 32 + kq + j]);
    if ((l >> 4) == 0) bsumL[m * 16 + rowl] = b_ih[orig] + b_hh[orig];
  }
}

// ------------------------------------------------------------------
// Kernel 1: attention. a[b,:] = softmax_d( sum_t x[b,t,d]*w_att[2H+t] )
// (h/c/b_att terms are uniform over d -> softmax-invariant -> dropped).
// ------------------------------------------------------------------
__global__ __launch_bounds__(256) void attn_kernel(const float* __restrict__ x,
                                                   const float* __restrict__ W_att,
                                                   float* __restrict__ out0) {
  int tid = threadIdx.x;
  int b = blockIdx.x * 32 + (tid >> 3);
  int dq = (tid & 7) * 4;
  const float* xb = x + (size_t)b * (TT * DD);
  float px = 0.f, py = 0.f, pz = 0.f, pw = 0.f;
#pragma unroll 4
  for (int t = 0; t < TT; ++t) {
    float w = W_att[2 * HH + t];
    float4 xv = *(const float4*)(xb + t * DD + dq);
    px = fmaf(xv.x, w, px);
    py = fmaf(xv.y, w, py);
    pz = fmaf(xv.z, w, pz);
    pw = fmaf(xv.w, w, pw);
  }
  float m = fmaxf(fmaxf(px, py), fmaxf(pz, pw));
#pragma unroll
  for (int s = 1; s < 8; s <<= 1) m = fmaxf(m, __shfl_xor(m, s));
  float ex = __expf(px - m), ey = __expf(py - m), ez = __expf(pz - m), ew = __expf(pw - m);
  float sum = ex + ey + ez + ew;
#pragma unroll
  for (int s = 1; s < 8; s <<= 1) sum += __shfl_xor(sum, s);
  float inv = __builtin_amdgcn_rcpf(sum);
  float4 a;
  a.x = ex * inv; a.y = ey * inv; a.z = ez * inv; a.w = ew * inv;
  float* o = out0 + (size_t)b * (TT * DD) + dq;
#pragma unroll 4
  for (int t = 0; t < TT; ++t) *(float4*)(o + t * DD) = a;
}

// ------------------------------------------------------------------
// Kernel 2: wave-pair LSTM, weights FULLY register-resident (160 VGPR/wave).
// 512 blocks x 256 thr = 2048 waves = 2 waves/SIMD. Block = 2 pairs; each
// pair owns 16 batch rows; wave `half` computes gates for h-chunk
// [half*32, half*32+32) (8 m-tiles, 40 MFMAs/step, 8 pointwise elems/lane).
// h-chunk exchange: 16B/lane LDS write+read, double-buffered, 1 barrier/step.
// ------------------------------------------------------------------
__global__ __launch_bounds__(256, 2) void lstm_kernel(
    const float* __restrict__ x, const float* __restrict__ h0, const float* __restrict__ c0,
    const float* __restrict__ a_src, const unsigned short* __restrict__ WhhL,
    const unsigned short* __restrict__ WihL, const float* __restrict__ bsumL,
    float* __restrict__ out1) {
  __shared__ __align__(16) float sbias[256];
  __shared__ __align__(16) char xch[8192];  // [pair][buf][half][lane] * 16B
  const int tid = threadIdx.x;
  const int l = tid & 63;
  const int w = tid >> 6;
  const int pair = w >> 1;
  const int half = w & 1;
  const int b = l & 15;
  const int qp = l >> 4;
  const int brow = blockIdx.x * 32 + pair * 16 + b;

  sbias[tid] = bsumL[tid];

#define XOFF(pr, buf, hf) ((((pr) * 2 + (buf)) * 2 + (hf)) * 1024)

  // Own-half weights, fully resident: 8 tiles m = g*4 + 2*half + e.
  // whhO = k-chunk contracting with OWN h-chunk (c = half); whhX = other.
  f32x4 whhO[2][4][2], whhX[2][4][2], wihR[2][4];
#pragma unroll
  for (int e = 0; e < 2; ++e)
#pragma unroll
    for (int g = 0; g < 4; ++g) {
      const int m = g * 4 + 2 * half + e;
#pragma unroll
      for (int p = 0; p < 2; ++p) {
        whhO[e][g][p] = *(const f32x4*)(WhhL + (((p * 16 + m) * 2 + half) << 9) + l * 8);
        whhX[e][g][p] = *(const f32x4*)(WhhL + (((p * 16 + m) * 2 + (1 ^ half)) << 9) + l * 8);
      }
      wihR[e][g] = *(const f32x4*)(WihL + (m << 9) + l * 8);
    }
#pragma unroll
  for (int e = 0; e < 2; ++e)
#pragma unroll
    for (int g = 0; g < 4; ++g) {
#pragma unroll
      for (int p = 0; p < 2; ++p) {
        asm volatile("" : "+v"(whhO[e][g][p]));
        asm volatile("" : "+v"(whhX[e][g][p]));
      }
      asm volatile("" : "+v"(wihR[e][g]));
    }

  // attention weights for this lane's d-slots (d = qp*8 + j)
  float av[8];
  {
    const float* ap = a_src + (size_t)brow * (TT * DD) + qp * 8;
    float4 a0 = *(const float4*)ap, a1 = *(const float4*)(ap + 4);
    av[0] = a0.x; av[1] = a0.y; av[2] = a0.z; av[3] = a0.w;
    av[4] = a1.x; av[5] = a1.y; av[6] = a1.z; av[7] = a1.w;
  }

  // c state: creg[e][r] = c[brow][half*32 + qp*8 + e*4 + r]
  f32x4 creg[2];
#pragma unroll
  for (int e = 0; e < 2; ++e)
    creg[e] = *(const f32x4*)(c0 + (size_t)brow * HH + half * 32 + qp * 8 + e * 4);

  // own h chunk (single bf16) + publish to exchange buf 0
  bf16x8 own;
  {
    const float* hp = h0 + (size_t)brow * HH + half * 32 + qp * 8;
    float4 v0 = *(const float4*)hp, v1 = *(const float4*)(hp + 4);
    float vv[8] = {v0.x, v0.y, v0.z, v0.w, v1.x, v1.y, v1.z, v1.w};
#pragma unroll
    for (int j = 0; j < 8; ++j) own[j] = (__bf16)vv[j];
    *(f32x4*)(xch + XOFF(pair, 0, half) + l * 16) = __builtin_bit_cast(f32x4, own);
  }

  const float* xp = x + (size_t)brow * (TT * DD) + qp * 8;
  float* op = out1 + (size_t)brow * (TT * HH) + half * 32 + qp * 8;
  float xv[8];
  {
    float4 x0 = *(const float4*)xp, x1 = *(const float4*)(xp + 4);
    xv[0] = x0.x; xv[1] = x0.y; xv[2] = x0.z; xv[3] = x0.w;
    xv[4] = x1.x; xv[5] = x1.y; xv[6] = x1.z; xv[7] = x1.w;
  }
  __syncthreads();

  for (int t = 0; t < TT; ++t) {
    const int cur = t & 1, nxt = cur ^ 1;
    // partner's h chunk from current exchange buffer
    bf16x8 oth = BC(*(const f32x4*)(xch + XOFF(pair, cur, 1 ^ half) + l * 16));
    // xw for this step
    bf16x8 bxw;
#pragma unroll
    for (int j = 0; j < 8; ++j) bxw[j] = (__bf16)(xv[j] * av[j]);
    // prefetch next x (clamped; final load is dead but harmless)
    const int tn = (t + 1 < TT) ? (t + 1) : (TT - 1);
    float xn[8];
    {
      const float* xnp = xp + (size_t)tn * DD;
      float4 x0 = *(const float4*)xnp, x1 = *(const float4*)(xnp + 4);
      xn[0] = x0.x; xn[1] = x0.y; xn[2] = x0.z; xn[3] = x0.w;
      xn[4] = x1.x; xn[5] = x1.y; xn[6] = x1.z; xn[7] = x1.w;
    }

    bf16x8 ownNew;
#pragma unroll
    for (int e = 0; e < 2; ++e) {
      f32x4 acc[4];
#pragma unroll
      for (int g = 0; g < 4; ++g) {
        const int m = g * 4 + 2 * half + e;
        f32x4 A = *(const f32x4*)(sbias + m * 16 + qp * 4);  // broadcast, conflict-free
        A = MFMA(BC(whhO[e][g][0]), own, A);  // own-chunk k: Whi*h
        A = MFMA(BC(whhO[e][g][1]), own, A);  //              Wlo*h
        A = MFMA(BC(whhX[e][g][0]), oth, A);  // other-chunk: Whi*h
        A = MFMA(BC(whhX[e][g][1]), oth, A);  //              Wlo*h
        A = MFMA(BC(wihR[e][g]), bxw, A);     // input chunk
        acc[g] = A;
      }
      float hr[4];
#pragma unroll
      for (int r = 0; r < 4; ++r) {
        float ig = sigm(acc[0][r]);
        float fg = sigm(acc[1][r]);
        float gt = tanh_f(acc[2][r]);
        float og = sigm(acc[3][r]);
        float cn = fg * creg[e][r] + ig * gt;
        creg[e][r] = cn;
        hr[r] = og * tanh_f(cn);
      }
      float4 hv;
      hv.x = hr[0]; hv.y = hr[1]; hv.z = hr[2]; hv.w = hr[3];
      *(float4*)(op + (size_t)t * HH + e * 4) = hv;  // pair covers full 256B row
#pragma unroll
      for (int r = 0; r < 4; ++r) ownNew[e * 4 + r] = (__bf16)hr[r];
    }
    own = ownNew;
    // publish own new chunk for the partner's next step
    *(f32x4*)(xch + XOFF(pair, nxt, half) + l * 16) = __builtin_bit_cast(f32x4, own);
#pragma unroll
    for (int j = 0; j < 8; ++j) xv[j] = xn[j];
    __syncthreads();
  }
#undef XOFF
}

extern "C" void kernel_launch(void* const* d_in, const int* in_sizes, int n_in,
                              void* d_out, int out_size, void* d_ws, size_t ws_size,
                              hipStream_t stream) {
  const float* x = (const float*)d_in[0];
  const float* h0 = (const float*)d_in[1];
  const float* c0 = (const float*)d_in[2];
  const float* W_att = (const float*)d_in[3];
  // d_in[4] = b_att: uniform shift, softmax-invariant -> unused
  const float* W_ih = (const float*)d_in[5];
  const float* W_hh = (const float*)d_in[6];
  const float* b_ih = (const float*)d_in[7];
  const float* b_hh = (const float*)d_in[8];

  float* out0 = (float*)d_out;                // attention [B,T,D]
  float* out1 = out0 + (size_t)BB * TT * DD;  // input_encoded [B,T,H]

  char* ws = (char*)d_ws;
  unsigned short* WhhL = (unsigned short*)ws;            // 65536 B
  unsigned short* WihL = (unsigned short*)(ws + 65536);  // 16384 B
  float* bsumL = (float*)(ws + 81920);                   // 1024 B

  prep_kernel<<<1, 256, 0, stream>>>(W_ih, W_hh, b_ih, b_hh, WhhL, WihL, bsumL);
  attn_kernel<<<BB / 32, 256, 0, stream>>>(x, W_att, out0);
  // lstm reads a[b,d] from the t=0 slice of out0 (== a broadcast over t)
  lstm_kernel<<<BB / 32, 256, 0, stream>>>(x, h0, c0, out0, WhhL, WihL, bsumL, out1);
}

// Round 11
// 159.830 us; speedup vs baseline: 1.3237x; 1.0266x over previous
//
#include <hip/hip_runtime.h>

#define TT 48
#define DD 32
#define HH 64
#define BB 16384
#define LOG2E 1.4426950408889634f

typedef __bf16 bf16x8 __attribute__((ext_vector_type(8)));
typedef float f32x4 __attribute__((ext_vector_type(4)));

#define MFMA(a, b, c) __builtin_amdgcn_mfma_f32_16x16x32_bf16(a, b, c, 0, 0, 0)
#define BC(v) __builtin_bit_cast(bf16x8, v)

static __device__ __forceinline__ float exp2_f(float v) {
#if __has_builtin(__builtin_amdgcn_exp2f)
  return __builtin_amdgcn_exp2f(v);
#else
  return exp2f(v);
#endif
}
static __device__ __forceinline__ unsigned short bfu(float f) {
  __bf16 b = (__bf16)f;
  return __builtin_bit_cast(unsigned short, b);
}
static __device__ __forceinline__ float bff(unsigned short u) {
  return (float)__builtin_bit_cast(__bf16, u);
}
// pre-scaled domain (y = x*log2e): sigmoid(x) = rcp(1 + 2^-y)
static __device__ __forceinline__ float sigm2(float y) {
  return __builtin_amdgcn_rcpf(1.f + exp2_f(-y));
}
// pre-scaled domain (y = 2x*log2e): tanh(x) = 1 - 2*rcp(1 + 2^y)
static __device__ __forceinline__ float tanh2(float y) {
  return fmaf(-2.f, __builtin_amdgcn_rcpf(1.f + exp2_f(y)), 1.f);
}

// ------------------------------------------------------------------
// Row bijection: tile m = g*4+hq, tile-row = qp*4+r.
//   hidx(hq,qp,r) = (hq>>1)*32 + qp*8 + (hq&1)*4 + r
// Wave `half` of a pair owns hq in {2*half, 2*half+1}: its D outputs are
// exactly h-chunk [half*32, half*32+32) = its own next-step B-frag slots.
// The other chunk comes from the partner wave via a 16B/lane LDS exchange.
// ------------------------------------------------------------------

// Kernel 0: linearize W into per-lane MFMA A-fragment order, pre-scaled into
// the exp2 domain: i/f/o rows (and bias) * log2e, g rows * 2*log2e.
__global__ void prep_kernel(const float* __restrict__ W_ih, const float* __restrict__ W_hh,
                            const float* __restrict__ b_ih, const float* __restrict__ b_hh,
                            unsigned short* __restrict__ WhhL, unsigned short* __restrict__ WihL,
                            float* __restrict__ bsumL) {
  const int tid = threadIdx.x;  // 256 threads, 1 block
  const int l = tid & 63, qt = tid >> 6;
  const int rowl = l & 15, kq = (l >> 4) * 8;
  for (int mm = 0; mm < 4; ++mm) {
    const int m = qt * 4 + mm;
    const int g = m >> 2, hq = m & 3;
    const float s = (g == 2) ? 2.f * LOG2E : LOG2E;
    const int hidx = (hq >> 1) * 32 + (rowl >> 2) * 8 + (hq & 1) * 4 + (rowl & 3);
    const int orig = g * 64 + hidx;
    for (int c = 0; c < 2; ++c)
      for (int j = 0; j < 8; ++j) {
        float w = W_hh[orig * 64 + c * 32 + kq + j] * s;
        unsigned short hi = bfu(w);
        WhhL[((0 * 16 + m) * 2 + c) * 512 + l * 8 + j] = hi;
        WhhL[((1 * 16 + m) * 2 + c) * 512 + l * 8 + j] = bfu(w - bff(hi));
      }
    for (int j = 0; j < 8; ++j)
      WihL[m * 512 + l * 8 + j] = bfu(W_ih[orig * 32 + kq + j] * s);
    if ((l >> 4) == 0) bsumL[m * 16 + rowl] = (b_ih[orig] + b_hh[orig]) * s;
  }
}

// ------------------------------------------------------------------
// Kernel 1: attention. a[b,:] = softmax_d( sum_t x[b,t,d]*w_att[2H+t] )
// (h/c/b_att terms are uniform over d -> softmax-invariant -> dropped).
// ------------------------------------------------------------------
__global__ __launch_bounds__(256) void attn_kernel(const float* __restrict__ x,
                                                   const float* __restrict__ W_att,
                                                   float* __restrict__ out0) {
  int tid = threadIdx.x;
  int b = blockIdx.x * 32 + (tid >> 3);
  int dq = (tid & 7) * 4;
  const float* xb = x + (size_t)b * (TT * DD);
  float px = 0.f, py = 0.f, pz = 0.f, pw = 0.f;
#pragma unroll 4
  for (int t = 0; t < TT; ++t) {
    float w = W_att[2 * HH + t];
    float4 xv = *(const float4*)(xb + t * DD + dq);
    px = fmaf(xv.x, w, px);
    py = fmaf(xv.y, w, py);
    pz = fmaf(xv.z, w, pz);
    pw = fmaf(xv.w, w, pw);
  }
  float m = fmaxf(fmaxf(px, py), fmaxf(pz, pw));
#pragma unroll
  for (int s = 1; s < 8; s <<= 1) m = fmaxf(m, __shfl_xor(m, s));
  float ex = __expf(px - m), ey = __expf(py - m), ez = __expf(pz - m), ew = __expf(pw - m);
  float sum = ex + ey + ez + ew;
#pragma unroll
  for (int s = 1; s < 8; s <<= 1) sum += __shfl_xor(sum, s);
  float inv = __builtin_amdgcn_rcpf(sum);
  float4 a;
  a.x = ex * inv; a.y = ey * inv; a.z = ez * inv; a.w = ew * inv;
  float* o = out0 + (size_t)b * (TT * DD) + dq;
#pragma unroll 4
  for (int t = 0; t < TT; ++t) *(float4*)(o + t * DD) = a;
}

// ------------------------------------------------------------------
// Kernel 2: wave-pair LSTM, one pair per 128-thread block (barrier couples
// ONLY the producer/consumer pair). 1024 blocks = 2048 waves = 8 waves/CU
// (the gremlin-safe level). Wave `half` computes gates for h-chunk
// [half*32, half*32+32): 8 m-tiles, 40 MFMAs/step, 8 pointwise elems/lane,
// weights fully register-resident (160 VGPR). Pointwise in exp2 domain.
// ------------------------------------------------------------------
__global__ __launch_bounds__(128, 2) void lstm_kernel(
    const float* __restrict__ x, const float* __restrict__ h0, const float* __restrict__ c0,
    const float* __restrict__ a_src, const unsigned short* __restrict__ WhhL,
    const unsigned short* __restrict__ WihL, const float* __restrict__ bsumL,
    float* __restrict__ out1) {
  __shared__ __align__(16) float sbias[256];
  __shared__ __align__(16) char xch[4096];  // [buf][half][lane] * 16B
  const int tid = threadIdx.x;
  const int l = tid & 63;
  const int half = tid >> 6;
  const int b = l & 15;
  const int qp = l >> 4;
  const int brow = blockIdx.x * 16 + b;

  sbias[tid] = bsumL[tid];
  sbias[tid + 128] = bsumL[tid + 128];

#define XOFF(buf, hf) (((buf) * 2 + (hf)) * 1024)

  // Own-half weights, fully resident: 8 tiles m = g*4 + 2*half + e.
  // whhO = k-chunk contracting with OWN h-chunk (c = half); whhX = other.
  f32x4 whhO[2][4][2], whhX[2][4][2], wihR[2][4];
#pragma unroll
  for (int e = 0; e < 2; ++e)
#pragma unroll
    for (int g = 0; g < 4; ++g) {
      const int m = g * 4 + 2 * half + e;
#pragma unroll
      for (int p = 0; p < 2; ++p) {
        whhO[e][g][p] = *(const f32x4*)(WhhL + (((p * 16 + m) * 2 + half) << 9) + l * 8);
        whhX[e][g][p] = *(const f32x4*)(WhhL + (((p * 16 + m) * 2 + (1 ^ half)) << 9) + l * 8);
      }
      wihR[e][g] = *(const f32x4*)(WihL + (m << 9) + l * 8);
    }
#pragma unroll
  for (int e = 0; e < 2; ++e)
#pragma unroll
    for (int g = 0; g < 4; ++g) {
#pragma unroll
      for (int p = 0; p < 2; ++p) {
        asm volatile("" : "+v"(whhO[e][g][p]));
        asm volatile("" : "+v"(whhX[e][g][p]));
      }
      asm volatile("" : "+v"(wihR[e][g]));
    }

  // attention weights for this lane's d-slots (d = qp*8 + j)
  float av[8];
  {
    const float* ap = a_src + (size_t)brow * (TT * DD) + qp * 8;
    float4 a0 = *(const float4*)ap, a1 = *(const float4*)(ap + 4);
    av[0] = a0.x; av[1] = a0.y; av[2] = a0.z; av[3] = a0.w;
    av[4] = a1.x; av[5] = a1.y; av[6] = a1.z; av[7] = a1.w;
  }

  // c state: creg[e][r] = c[brow][half*32 + qp*8 + e*4 + r]
  f32x4 creg[2];
#pragma unroll
  for (int e = 0; e < 2; ++e)
    creg[e] = *(const f32x4*)(c0 + (size_t)brow * HH + half * 32 + qp * 8 + e * 4);

  // own h chunk (single bf16) + publish to exchange buf 0
  bf16x8 own;
  {
    const float* hp = h0 + (size_t)brow * HH + half * 32 + qp * 8;
    float4 v0 = *(const float4*)hp, v1 = *(const float4*)(hp + 4);
    float vv[8] = {v0.x, v0.y, v0.z, v0.w, v1.x, v1.y, v1.z, v1.w};
#pragma unroll
    for (int j = 0; j < 8; ++j) own[j] = (__bf16)vv[j];
    *(f32x4*)(xch + XOFF(0, half) + l * 16) = __builtin_bit_cast(f32x4, own);
  }

  const float* xp = x + (size_t)brow * (TT * DD) + qp * 8;
  float* op = out1 + (size_t)brow * (TT * HH) + half * 32 + qp * 8;
  float xv[8];
  {
    float4 x0 = *(const float4*)xp, x1 = *(const float4*)(xp + 4);
    xv[0] = x0.x; xv[1] = x0.y; xv[2] = x0.z; xv[3] = x0.w;
    xv[4] = x1.x; xv[5] = x1.y; xv[6] = x1.z; xv[7] = x1.w;
  }
  __syncthreads();

  for (int t = 0; t < TT; ++t) {
    const int cur = t & 1, nxt = cur ^ 1;
    // partner's h chunk from current exchange buffer
    bf16x8 oth = BC(*(const f32x4*)(xch + XOFF(cur, 1 ^ half) + l * 16));
    // xw for this step
    bf16x8 bxw;
#pragma unroll
    for (int j = 0; j < 8; ++j) bxw[j] = (__bf16)(xv[j] * av[j]);
    // prefetch next x (clamped; final load is dead but harmless)
    const int tn = (t + 1 < TT) ? (t + 1) : (TT - 1);
    float xn[8];
    {
      const float* xnp = xp + (size_t)tn * DD;
      float4 x0 = *(const float4*)xnp, x1 = *(const float4*)(xnp + 4);
      xn[0] = x0.x; xn[1] = x0.y; xn[2] = x0.z; xn[3] = x0.w;
      xn[4] = x1.x; xn[5] = x1.y; xn[6] = x1.z; xn[7] = x1.w;
    }

    bf16x8 ownNew;
#pragma unroll
    for (int e = 0; e < 2; ++e) {
      f32x4 acc[4];
#pragma unroll
      for (int g = 0; g < 4; ++g) {
        const int m = g * 4 + 2 * half + e;
        f32x4 A = *(const f32x4*)(sbias + m * 16 + qp * 4);  // broadcast, conflict-free
        A = MFMA(BC(whhO[e][g][0]), own, A);  // own-chunk k: Whi*h
        A = MFMA(BC(whhO[e][g][1]), own, A);  //              Wlo*h
        A = MFMA(BC(whhX[e][g][0]), oth, A);  // other-chunk: Whi*h
        A = MFMA(BC(whhX[e][g][1]), oth, A);  //              Wlo*h
        A = MFMA(BC(wihR[e][g]), bxw, A);     // input chunk
        acc[g] = A;
      }
      float hr[4];
#pragma unroll
      for (int r = 0; r < 4; ++r) {
        float ig = sigm2(acc[0][r]);
        float fg = sigm2(acc[1][r]);
        float gt = tanh2(acc[2][r]);   // g rows pre-scaled by 2*log2e
        float og = sigm2(acc[3][r]);
        float cn = fg * creg[e][r] + ig * gt;
        creg[e][r] = cn;
        hr[r] = og * tanh2(2.f * LOG2E * cn);
      }
      float4 hv;
      hv.x = hr[0]; hv.y = hr[1]; hv.z = hr[2]; hv.w = hr[3];
      *(float4*)(op + (size_t)t * HH + e * 4) = hv;  // pair covers full 256B row
#pragma unroll
      for (int r = 0; r < 4; ++r) ownNew[e * 4 + r] = (__bf16)hr[r];
    }
    own = ownNew;
    // publish own new chunk for the partner's next step
    *(f32x4*)(xch + XOFF(nxt, half) + l * 16) = __builtin_bit_cast(f32x4, own);
#pragma unroll
    for (int j = 0; j < 8; ++j) xv[j] = xn[j];
    __syncthreads();
  }
#undef XOFF
}

extern "C" void kernel_launch(void* const* d_in, const int* in_sizes, int n_in,
                              void* d_out, int out_size, void* d_ws, size_t ws_size,
                              hipStream_t stream) {
  const float* x = (const float*)d_in[0];
  const float* h0 = (const float*)d_in[1];
  const float* c0 = (const float*)d_in[2];
  const float* W_att = (const float*)d_in[3];
  // d_in[4] = b_att: uniform shift, softmax-invariant -> unused
  const float* W_ih = (const float*)d_in[5];
  const float* W_hh = (const float*)d_in[6];
  const float* b_ih = (const float*)d_in[7];
  const float* b_hh = (const float*)d_in[8];

  float* out0 = (float*)d_out;                // attention [B,T,D]
  float* out1 = out0 + (size_t)BB * TT * DD;  // input_encoded [B,T,H]

  char* ws = (char*)d_ws;
  unsigned short* WhhL = (unsigned short*)ws;            // 65536 B
  unsigned short* WihL = (unsigned short*)(ws + 65536);  // 16384 B
  float* bsumL = (float*)(ws + 81920);                   // 1024 B

  prep_kernel<<<1, 256, 0, stream>>>(W_ih, W_hh, b_ih, b_hh, WhhL, WihL, bsumL);
  attn_kernel<<<BB / 32, 256, 0, stream>>>(x, W_att, out0);
  // lstm reads a[b,d] from the t=0 slice of out0 (== a broadcast over t)
  lstm_kernel<<<BB / 16, 128, 0, stream>>>(x, h0, c0, out0, WhhL, WihL, bsumL, out1);
}